// Round 11
// baseline (690.390 us; speedup 1.0000x reference)
//
#include <hip/hip_runtime.h>

typedef unsigned short u16;
typedef unsigned int u32;

using short8 = __attribute__((ext_vector_type(8))) short;
using f32x4  = __attribute__((ext_vector_type(4))) float;
using f32x2  = __attribute__((ext_vector_type(2))) float;

#define SSEQ 512
#define BB   16
#define DD   256
#define G4   256      // 4*SS
#define SSZ  64       // SS
#define VV   10000
#define VPAD 10112    // 79*128
#define MALL 8192     // BB*SSEQ

// ---- ws layout (bytes) ----
#define OFF_XHI   0u
#define OFF_XLO   4194304u
#define OFF_WHI   8388608u
#define OFF_WLO   8519680u
#define OFF_WSY   8650752u
#define OFF_XPROJ 9945088u
#define OFF_HS    18333696u
#define OFF_PROG  19382272u

__device__ __forceinline__ u16 f2bf(float f) {
  u32 u = __float_as_uint(f);
  u32 r = (u + 0x7fffu + ((u >> 16) & 1u)) >> 16;
  return (u16)r;
}
__device__ __forceinline__ float bf2f(u16 h) {
  return __uint_as_float(((u32)h) << 16);
}
// packed dual-FMA: c += a*b elementwise
__device__ __forceinline__ f32x2 pkfma(f32x2 a, f32x2 b, f32x2 c) {
  asm("v_pk_fma_f32 %0, %1, %2, %0" : "+v"(c) : "v"(a), "v"(b));
  return c;
}
// quad butterfly add via DPP; CTRL 0xB1=xor1, 0x4E=xor2
template <int CTRL>
__device__ __forceinline__ float qadd(float x) {
  int pv = __builtin_amdgcn_update_dpp(0, __float_as_int(x), CTRL, 0xf, 0xf, true);
  return x + __int_as_float(pv);
}
// quad broadcast of lane: 0x00/0x55/0xAA/0xFF
template <int CTRL>
__device__ __forceinline__ float qbcast(float x) {
  int pv = __builtin_amdgcn_update_dpp(0, __float_as_int(x), CTRL, 0xf, 0xf, true);
  return __int_as_float(pv);
}

// ---------------- K0: fp32 -> bf16 conversions + prog zeroing -------------------
#define NX 2097152
#define NW 65536
#define NP 647168   // VPAD*64
__global__ void k0_convert(const float* __restrict__ x, const float* __restrict__ Wxs,
                           const float* __restrict__ Wsy,
                           u16* __restrict__ xhi, u16* __restrict__ xlo,
                           u16* __restrict__ whi, u16* __restrict__ wlo,
                           u16* __restrict__ wsyb, int* __restrict__ prog) {
  int i = blockIdx.x * 256 + threadIdx.x;
  if (i < NX) {
    float v = x[i]; u16 h = f2bf(v);
    xhi[i] = h; xlo[i] = f2bf(v - bf2f(h));
  } else if (i < NX + NW) {
    int j = i - NX;
    float v = Wxs[j]; u16 h = f2bf(v);
    whi[j] = h; wlo[j] = f2bf(v - bf2f(h));
  } else if (i < NX + NW + NP) {
    int j = i - NX - NW;
    wsyb[j] = (j < VV * SSZ) ? f2bf(Wsy[j]) : (u16)0;
  } else {
    int j = i - NX - NW - NP;
    if (j < BB)
      __hip_atomic_store(prog + j, 0, __ATOMIC_RELEASE, __HIP_MEMORY_SCOPE_AGENT);
  }
}

// ---------------- K1: xproj = x @ Wxs^T + b   (double-bf16 MFMA, fp32 out) ------
__global__ __launch_bounds__(256) void k1_xproj(
    const u16* __restrict__ xhi, const u16* __restrict__ xlo,
    const u16* __restrict__ whi, const u16* __restrict__ wlo,
    const float* __restrict__ bias, float* __restrict__ xproj) {
  int bid = blockIdx.x;
  int mb = bid >> 1, nb = bid & 1;
  int tid = threadIdx.x, l = tid & 63, wid = tid >> 6;
  int wm = wid >> 1, wv = wid & 1;
  int m0 = mb * 128 + wm * 64, n0 = nb * 128 + wv * 64;
  int lr = l & 15, lg = l >> 4;

  f32x4 acc[4][4];
#pragma unroll
  for (int a = 0; a < 4; a++)
#pragma unroll
    for (int bq = 0; bq < 4; bq++) acc[a][bq] = (f32x4){0.f, 0.f, 0.f, 0.f};

#pragma unroll
  for (int p = 0; p < 3; p++) {
    const u16* A = (p == 1) ? xlo : xhi;
    const u16* B = (p == 2) ? wlo : whi;
#pragma unroll
    for (int ks = 0; ks < 8; ks++) {
      short8 af[4], bf_[4];
#pragma unroll
      for (int fm = 0; fm < 4; fm++)
        af[fm] = *(const short8*)(A + (size_t)(m0 + fm * 16 + lr) * 256 + ks * 32 + lg * 8);
#pragma unroll
      for (int fv = 0; fv < 4; fv++)
        bf_[fv] = *(const short8*)(B + (size_t)(n0 + fv * 16 + lr) * 256 + ks * 32 + lg * 8);
#pragma unroll
      for (int fm = 0; fm < 4; fm++)
#pragma unroll
        for (int fv = 0; fv < 4; fv++)
          acc[fm][fv] = __builtin_amdgcn_mfma_f32_16x16x32_bf16(af[fm], bf_[fv], acc[fm][fv], 0, 0, 0);
    }
  }
#pragma unroll
  for (int fv = 0; fv < 4; fv++) {
    int j = n0 + fv * 16 + lr;
    float bj = bias[j];
#pragma unroll
    for (int fm = 0; fm < 4; fm++)
#pragma unroll
      for (int r = 0; r < 4; r++) {
        int m = m0 + fm * 16 + lg * 4 + r;
        xproj[(size_t)m * 256 + j] = acc[fm][fv][r] + bj;
      }
  }
}

// ---------------- K23: fused scan (blocks 0..15) + vocab GEMM (16..255) --------
// Scan: R5 structure, 8-deep xp prefetch (~6400 cyc cover vs contended HBM).
// Publishes prog[b] every 32 steps (vmcnt drain + barrier + agent release).
// GEMM: 32x128 tiles at the SAME 32-step granularity as publication -> smooth
// ~50%-duty write stream (16 x 20MB levels) instead of 4 x 82MB bursts; tail
// after scan end is one level (~6us). wsyb (1.3MB) stays L2-resident.
__global__ __launch_bounds__(256, 1) void k23_fused(
    const float* __restrict__ xproj, const float* __restrict__ Wss,
    const float* __restrict__ Wssb, u16* __restrict__ hsb,
    const u16* __restrict__ wsyb, const float* __restrict__ ybias,
    float* __restrict__ y, int* __restrict__ prog) {
  __shared__ float hbuf[2][64];
  int bid = blockIdx.x, tid = threadIdx.x;

  if (bid < BB) {
    // ================= scan block: batch b = bid =================
    int b = bid;
    int w = tid >> 6, l = tid & 63;
    int oo = l >> 2, ks = l & 3;
    int jj = w * 16 + oo;
    int ks16 = ks * 16;

    f32x2 wr[32];
#pragma unroll
    for (int g = 0; g < 4; g++) {
      const f32x2* pw = (const f32x2*)(Wss + (size_t)(g * 64 + jj) * 64 + ks16);
#pragma unroll
      for (int q = 0; q < 8; q++) wr[g * 8 + q] = pw[q];
    }
    float mybias = Wssb[ks * 64 + jj];

    float kk = (ks == 2) ? 2.885390082f : -1.442695041f;
    float Ac = (ks == 2) ? 1.f : 0.f;
    float Bc = (ks == 2) ? -2.f : 1.f;

    const float* xqp = xproj + (size_t)b * SSEQ * 256 + ks * 64 + jj;
    float xs0 = xqp[0 * 256];
    float xs1 = xqp[1 * 256];
    float xs2 = xqp[2 * 256];
    float xs3 = xqp[3 * 256];
    float xs4 = xqp[4 * 256];
    float xs5 = xqp[5 * 256];
    float xs6 = xqp[6 * 256];
    float xs7 = xqp[7 * 256];

    u16* hout = hsb + (size_t)b * SSEQ * 64 + jj;

    if (tid < 128) ((float*)hbuf)[tid] = 0.f;
    __syncthreads();

    float c = 0.f;

#define STEP(T, XS, RB, WB) { \
    f32x4 h4[4]; \
    const f32x4* hb = (const f32x4*)&hbuf[RB][ks16]; \
    h4[0] = hb[0]; h4[1] = hb[1]; h4[2] = hb[2]; h4[3] = hb[3]; \
    float p[4]; \
    _Pragma("unroll") \
    for (int g = 0; g < 4; g++) { \
      f32x2 a0 = (f32x2){0.f, 0.f}, a1 = (f32x2){0.f, 0.f}; \
      _Pragma("unroll") \
      for (int q = 0; q < 4; q++) { \
        f32x2 hA = (f32x2){h4[q][0], h4[q][1]}; \
        f32x2 hB = (f32x2){h4[q][2], h4[q][3]}; \
        a0 = pkfma(hA, wr[g * 8 + 2 * q], a0); \
        a1 = pkfma(hB, wr[g * 8 + 2 * q + 1], a1); \
      } \
      f32x2 ps = a0 + a1; \
      p[g] = ps[0] + ps[1]; \
    } \
    _Pragma("unroll") \
    for (int g = 0; g < 4; g++) p[g] = qadd<0x4E>(qadd<0xB1>(p[g])); \
    float myp = (ks == 1) ? p[1] : p[0]; \
    myp = (ks == 2) ? p[2] : myp; \
    myp = (ks == 3) ? p[3] : myp; \
    float aa = myp + XS + mybias; \
    if ((T) + 8 < SSEQ) XS = xqp[(size_t)((T) + 8) * 256]; \
    float z = exp2f(kk * aa); \
    float act = fmaf(Bc, __builtin_amdgcn_rcpf(z + 1.f), Ac); \
    float fg = qbcast<0x00>(act); \
    float ig = qbcast<0x55>(act); \
    float gg = qbcast<0xAA>(act); \
    float og = qbcast<0xFF>(act); \
    c = fmaf(c, fg, ig * gg); \
    float hn = og * c;  /* faithful to reference: no tanh(c) */ \
    if (ks == 0) { \
      hbuf[WB][jj] = hn; \
      __builtin_nontemporal_store(f2bf(hn), hout + (size_t)(T) * 64); \
    } \
    asm volatile("s_waitcnt lgkmcnt(0)\n\ts_barrier" ::: "memory"); \
  }

    for (int t = 0; t < SSEQ; t += 32) {
#pragma unroll
      for (int tq = 0; tq < 32; tq += 8) {
        STEP(t + tq + 0, xs0, 1, 0)
        STEP(t + tq + 1, xs1, 0, 1)
        STEP(t + tq + 2, xs2, 1, 0)
        STEP(t + tq + 3, xs3, 0, 1)
        STEP(t + tq + 4, xs4, 1, 0)
        STEP(t + tq + 5, xs5, 0, 1)
        STEP(t + tq + 6, xs6, 1, 0)
        STEP(t + tq + 7, xs7, 0, 1)
      }
      // publish progress: drain nt stores (all waves), sync, release store
      asm volatile("s_waitcnt vmcnt(0)" ::: "memory");
      __syncthreads();
      if (tid == 0)
        __hip_atomic_store(prog + b, t + 32, __ATOMIC_RELEASE, __HIP_MEMORY_SCOPE_AGENT);
    }
#undef STEP
  } else {
    // ================= GEMM block: 32x128 tiles, level-major sweep ==========
    // level = 32-step chunk; tiles/level = 16 batches x 79 vb = 1264.
    int gb = bid - BB;              // 0..239
    int l = tid & 63, wid = tid >> 6;
    int wm = wid >> 1, wv = wid & 1;     // wm: 16-row half, wv: 64-col half
    int lr = l & 15, lg = l >> 4;

    for (int idx = gb; idx < 16 * BB * 79; idx += 256 - BB) {
      int lvl = idx / (BB * 79);
      int rem = idx - lvl * (BB * 79);
      int b = rem / 79;
      int vb = rem - b * 79;
      int need = lvl * 32 + 32;

      while (__hip_atomic_load(prog + b, __ATOMIC_RELAXED, __HIP_MEMORY_SCOPE_AGENT) < need)
        __builtin_amdgcn_s_sleep(8);
      __builtin_amdgcn_fence(__ATOMIC_ACQUIRE, "agent");

      int m0 = b * SSEQ + lvl * 32 + wm * 16;
      int v0 = vb * 128 + wv * 64;

      f32x4 acc[4];  // [fv]; acc rows = 4 consecutive v, cols = m
#pragma unroll
      for (int a = 0; a < 4; a++) acc[a] = (f32x4){0.f, 0.f, 0.f, 0.f};

#pragma unroll
      for (int ks = 0; ks < 2; ks++) {
        short8 af = *(const short8*)(hsb + (size_t)(m0 + lr) * 64 + ks * 32 + lg * 8);
        short8 bf_[4];
#pragma unroll
        for (int fv = 0; fv < 4; fv++)
          bf_[fv] = *(const short8*)(wsyb + (size_t)(v0 + fv * 16 + lr) * 64 + ks * 32 + lg * 8);
#pragma unroll
        for (int fv = 0; fv < 4; fv++)
          acc[fv] = __builtin_amdgcn_mfma_f32_16x16x32_bf16(bf_[fv], af, acc[fv], 0, 0, 0);
      }

#pragma unroll
      for (int fv = 0; fv < 4; fv++) {
        int vb4 = v0 + fv * 16 + lg * 4;
        bool ok = (vb4 + 3) < VV;
        float4 bv = ok ? *(const float4*)(ybias + vb4) : float4{0.f, 0.f, 0.f, 0.f};
        int m = m0 + lr;
        if (ok) {
          float4 o;
          o.x = acc[fv][0] + bv.x;
          o.y = acc[fv][1] + bv.y;
          o.z = acc[fv][2] + bv.z;
          o.w = acc[fv][3] + bv.w;
          *(float4*)(y + (size_t)m * (size_t)VV + vb4) = o;
        }
      }
    }
  }
}

extern "C" void kernel_launch(void* const* d_in, const int* in_sizes, int n_in,
                              void* d_out, int out_size, void* d_ws, size_t ws_size,
                              hipStream_t stream) {
  const float* x     = (const float*)d_in[0];
  const float* Wxs_w = (const float*)d_in[1];
  const float* Wxs_b = (const float*)d_in[2];
  const float* Wss_w = (const float*)d_in[3];
  const float* Wss_b = (const float*)d_in[4];
  const float* Wsy_w = (const float*)d_in[5];
  const float* Wsy_b = (const float*)d_in[6];
  float* y = (float*)d_out;
  char* ws = (char*)d_ws;

  u16*   xhi   = (u16*)(ws + OFF_XHI);
  u16*   xlo   = (u16*)(ws + OFF_XLO);
  u16*   whi   = (u16*)(ws + OFF_WHI);
  u16*   wlo   = (u16*)(ws + OFF_WLO);
  u16*   wsyb  = (u16*)(ws + OFF_WSY);
  float* xproj = (float*)(ws + OFF_XPROJ);
  u16*   hsb   = (u16*)(ws + OFF_HS);
  int*   prog  = (int*)(ws + OFF_PROG);

  k0_convert<<<(NX + NW + NP) / 256 + 1, 256, 0, stream>>>(
      x, Wxs_w, Wsy_w, xhi, xlo, whi, wlo, wsyb, prog);
  k1_xproj<<<128, 256, 0, stream>>>(xhi, xlo, whi, wlo, Wxs_b, xproj);
  k23_fused<<<256, 256, 0, stream>>>(xproj, Wss_w, Wss_b, hsb, wsyb, Wsy_b, y, prog);
}

// Round 12
// 285.569 us; speedup vs baseline: 2.4176x; 2.4176x over previous
//
#include <hip/hip_runtime.h>

typedef unsigned short u16;
typedef unsigned int u32;

using short8 = __attribute__((ext_vector_type(8))) short;
using f32x4  = __attribute__((ext_vector_type(4))) float;
using f32x2  = __attribute__((ext_vector_type(2))) float;

#define SSEQ 512
#define BB   16
#define DD   256
#define G4   256      // 4*SS
#define SSZ  64       // SS
#define VV   10000
#define VPAD 10112    // 79*128
#define MALL 8192     // BB*SSEQ

// ---- ws layout (bytes) ----
#define OFF_XHI   0u
#define OFF_XLO   4194304u
#define OFF_WHI   8388608u
#define OFF_WLO   8519680u
#define OFF_WSY   8650752u
#define OFF_XPROJ 9945088u
#define OFF_HS    18333696u
#define OFF_PROG  19382272u

__device__ __forceinline__ u16 f2bf(float f) {
  u32 u = __float_as_uint(f);
  u32 r = (u + 0x7fffu + ((u >> 16) & 1u)) >> 16;
  return (u16)r;
}
__device__ __forceinline__ float bf2f(u16 h) {
  return __uint_as_float(((u32)h) << 16);
}
// packed dual-FMA: c += a*b elementwise
__device__ __forceinline__ f32x2 pkfma(f32x2 a, f32x2 b, f32x2 c) {
  asm("v_pk_fma_f32 %0, %1, %2, %0" : "+v"(c) : "v"(a), "v"(b));
  return c;
}
// quad butterfly add via DPP; CTRL 0xB1=xor1, 0x4E=xor2
template <int CTRL>
__device__ __forceinline__ float qadd(float x) {
  int pv = __builtin_amdgcn_update_dpp(0, __float_as_int(x), CTRL, 0xf, 0xf, true);
  return x + __int_as_float(pv);
}
// quad broadcast of lane: 0x00/0x55/0xAA/0xFF
template <int CTRL>
__device__ __forceinline__ float qbcast(float x) {
  int pv = __builtin_amdgcn_update_dpp(0, __float_as_int(x), CTRL, 0xf, 0xf, true);
  return __int_as_float(pv);
}

// ---------------- K0: fp32 -> bf16 conversions + prog zeroing -------------------
#define NX 2097152
#define NW 65536
#define NP 647168   // VPAD*64
__global__ void k0_convert(const float* __restrict__ x, const float* __restrict__ Wxs,
                           const float* __restrict__ Wsy,
                           u16* __restrict__ xhi, u16* __restrict__ xlo,
                           u16* __restrict__ whi, u16* __restrict__ wlo,
                           u16* __restrict__ wsyb, int* __restrict__ prog) {
  int i = blockIdx.x * 256 + threadIdx.x;
  if (i < NX) {
    float v = x[i]; u16 h = f2bf(v);
    xhi[i] = h; xlo[i] = f2bf(v - bf2f(h));
  } else if (i < NX + NW) {
    int j = i - NX;
    float v = Wxs[j]; u16 h = f2bf(v);
    whi[j] = h; wlo[j] = f2bf(v - bf2f(h));
  } else if (i < NX + NW + NP) {
    int j = i - NX - NW;
    wsyb[j] = (j < VV * SSZ) ? f2bf(Wsy[j]) : (u16)0;
  } else {
    int j = i - NX - NW - NP;
    if (j < BB)
      __hip_atomic_store(prog + j, 0, __ATOMIC_RELEASE, __HIP_MEMORY_SCOPE_AGENT);
  }
}

// ---------------- K1: xproj = x @ Wxs^T + b   (double-bf16 MFMA, fp32 out) ------
__global__ __launch_bounds__(256) void k1_xproj(
    const u16* __restrict__ xhi, const u16* __restrict__ xlo,
    const u16* __restrict__ whi, const u16* __restrict__ wlo,
    const float* __restrict__ bias, float* __restrict__ xproj) {
  int bid = blockIdx.x;
  int mb = bid >> 1, nb = bid & 1;
  int tid = threadIdx.x, l = tid & 63, wid = tid >> 6;
  int wm = wid >> 1, wv = wid & 1;
  int m0 = mb * 128 + wm * 64, n0 = nb * 128 + wv * 64;
  int lr = l & 15, lg = l >> 4;

  f32x4 acc[4][4];
#pragma unroll
  for (int a = 0; a < 4; a++)
#pragma unroll
    for (int bq = 0; bq < 4; bq++) acc[a][bq] = (f32x4){0.f, 0.f, 0.f, 0.f};

#pragma unroll
  for (int p = 0; p < 3; p++) {
    const u16* A = (p == 1) ? xlo : xhi;
    const u16* B = (p == 2) ? wlo : whi;
#pragma unroll
    for (int ks = 0; ks < 8; ks++) {
      short8 af[4], bf_[4];
#pragma unroll
      for (int fm = 0; fm < 4; fm++)
        af[fm] = *(const short8*)(A + (size_t)(m0 + fm * 16 + lr) * 256 + ks * 32 + lg * 8);
#pragma unroll
      for (int fv = 0; fv < 4; fv++)
        bf_[fv] = *(const short8*)(B + (size_t)(n0 + fv * 16 + lr) * 256 + ks * 32 + lg * 8);
#pragma unroll
      for (int fm = 0; fm < 4; fm++)
#pragma unroll
        for (int fv = 0; fv < 4; fv++)
          acc[fm][fv] = __builtin_amdgcn_mfma_f32_16x16x32_bf16(af[fm], bf_[fv], acc[fm][fv], 0, 0, 0);
    }
  }
#pragma unroll
  for (int fv = 0; fv < 4; fv++) {
    int j = n0 + fv * 16 + lr;
    float bj = bias[j];
#pragma unroll
    for (int fm = 0; fm < 4; fm++)
#pragma unroll
      for (int r = 0; r < 4; r++) {
        int m = m0 + fm * 16 + lg * 4 + r;
        xproj[(size_t)m * 256 + j] = acc[fm][fv][r] + bj;
      }
  }
}

// ---------------- K23: fused scan (blocks 0..15) + vocab GEMM (16..255) --------
// Scan: R5 structure (4-deep prefetch). prog[b] published every 32 steps.
// GEMM: 128x128 tiles, t-major; ONE thread polls (s_sleep 64), then barrier +
// block-wide acquire fence. 256 blocks = 1/CU -> co-resident, no deadlock.
__global__ __launch_bounds__(256, 1) void k23_fused(
    const float* __restrict__ xproj, const float* __restrict__ Wss,
    const float* __restrict__ Wssb, u16* __restrict__ hsb,
    const u16* __restrict__ wsyb, const float* __restrict__ ybias,
    float* __restrict__ y, int* __restrict__ prog) {
  __shared__ float hbuf[2][64];
  int bid = blockIdx.x, tid = threadIdx.x;

  if (bid < BB) {
    // ================= scan block: batch b = bid =================
    int b = bid;
    int w = tid >> 6, l = tid & 63;
    int oo = l >> 2, ks = l & 3;
    int jj = w * 16 + oo;
    int ks16 = ks * 16;

    f32x2 wr[32];
#pragma unroll
    for (int g = 0; g < 4; g++) {
      const f32x2* pw = (const f32x2*)(Wss + (size_t)(g * 64 + jj) * 64 + ks16);
#pragma unroll
      for (int q = 0; q < 8; q++) wr[g * 8 + q] = pw[q];
    }
    float mybias = Wssb[ks * 64 + jj];

    float kk = (ks == 2) ? 2.885390082f : -1.442695041f;
    float Ac = (ks == 2) ? 1.f : 0.f;
    float Bc = (ks == 2) ? -2.f : 1.f;

    const float* xqp = xproj + (size_t)b * SSEQ * 256 + ks * 64 + jj;
    float xs0 = xqp[0 * 256];
    float xs1 = xqp[1 * 256];
    float xs2 = xqp[2 * 256];
    float xs3 = xqp[3 * 256];

    u16* hout = hsb + (size_t)b * SSEQ * 64 + jj;

    if (tid < 128) ((float*)hbuf)[tid] = 0.f;
    __syncthreads();

    float c = 0.f;

#define STEP(T, XS, RB, WB) { \
    f32x4 h4[4]; \
    const f32x4* hb = (const f32x4*)&hbuf[RB][ks16]; \
    h4[0] = hb[0]; h4[1] = hb[1]; h4[2] = hb[2]; h4[3] = hb[3]; \
    float p[4]; \
    _Pragma("unroll") \
    for (int g = 0; g < 4; g++) { \
      f32x2 a0 = (f32x2){0.f, 0.f}, a1 = (f32x2){0.f, 0.f}; \
      _Pragma("unroll") \
      for (int q = 0; q < 4; q++) { \
        f32x2 hA = (f32x2){h4[q][0], h4[q][1]}; \
        f32x2 hB = (f32x2){h4[q][2], h4[q][3]}; \
        a0 = pkfma(hA, wr[g * 8 + 2 * q], a0); \
        a1 = pkfma(hB, wr[g * 8 + 2 * q + 1], a1); \
      } \
      f32x2 ps = a0 + a1; \
      p[g] = ps[0] + ps[1]; \
    } \
    _Pragma("unroll") \
    for (int g = 0; g < 4; g++) p[g] = qadd<0x4E>(qadd<0xB1>(p[g])); \
    float myp = (ks == 1) ? p[1] : p[0]; \
    myp = (ks == 2) ? p[2] : myp; \
    myp = (ks == 3) ? p[3] : myp; \
    float aa = myp + XS + mybias; \
    if ((T) + 4 < SSEQ) XS = xqp[(size_t)((T) + 4) * 256]; \
    float z = exp2f(kk * aa); \
    float act = fmaf(Bc, __builtin_amdgcn_rcpf(z + 1.f), Ac); \
    float fg = qbcast<0x00>(act); \
    float ig = qbcast<0x55>(act); \
    float gg = qbcast<0xAA>(act); \
    float og = qbcast<0xFF>(act); \
    c = fmaf(c, fg, ig * gg); \
    float hn = og * c;  /* faithful to reference: no tanh(c) */ \
    if (ks == 0) { \
      hbuf[WB][jj] = hn; \
      __builtin_nontemporal_store(f2bf(hn), hout + (size_t)(T) * 64); \
    } \
    asm volatile("s_waitcnt lgkmcnt(0)\n\ts_barrier" ::: "memory"); \
  }

    for (int t = 0; t < SSEQ; t += 32) {
#pragma unroll
      for (int tq = 0; tq < 32; tq += 4) {
        STEP(t + tq + 0, xs0, 1, 0)
        STEP(t + tq + 1, xs1, 0, 1)
        STEP(t + tq + 2, xs2, 1, 0)
        STEP(t + tq + 3, xs3, 0, 1)
      }
      // publish progress: drain nt stores (all waves), sync, release store
      asm volatile("s_waitcnt vmcnt(0)" ::: "memory");
      __syncthreads();
      if (tid == 0)
        __hip_atomic_store(prog + b, t + 32, __ATOMIC_RELEASE, __HIP_MEMORY_SCOPE_AGENT);
    }
#undef STEP
  } else {
    // ================= GEMM block: t-major 128x128 tile sweep =================
    int gb = bid - BB;              // 0..239
    int l = tid & 63, wid = tid >> 6;
    int wm = wid >> 1, wv = wid & 1;
    int lr = l & 15, lg = l >> 4;

    for (int idx = gb; idx < 4 * BB * 79; idx += 256 - BB) {
      int tb = idx / (BB * 79);
      int rem = idx - tb * BB * 79;
      int b = rem / 79;
      int vb = rem - b * 79;
      int need = tb * 128 + 128;

      // single-thread poll; others park at the barrier (256x less poll traffic)
      if (tid == 0) {
        while (__hip_atomic_load(prog + b, __ATOMIC_RELAXED, __HIP_MEMORY_SCOPE_AGENT) < need)
          __builtin_amdgcn_s_sleep(64);
      }
      __syncthreads();
      __builtin_amdgcn_fence(__ATOMIC_ACQUIRE, "agent");

      int m0 = b * SSEQ + tb * 128 + wm * 64;
      int v0 = vb * 128 + wv * 64;

      f32x4 acc[4][4];  // [fv][fm]
#pragma unroll
      for (int a = 0; a < 4; a++)
#pragma unroll
        for (int bq = 0; bq < 4; bq++) acc[a][bq] = (f32x4){0.f, 0.f, 0.f, 0.f};

#pragma unroll
      for (int ks = 0; ks < 2; ks++) {
        short8 af[4], bf_[4];
#pragma unroll
        for (int fm = 0; fm < 4; fm++)
          af[fm] = *(const short8*)(hsb + (size_t)(m0 + fm * 16 + lr) * 64 + ks * 32 + lg * 8);
#pragma unroll
        for (int fv = 0; fv < 4; fv++)
          bf_[fv] = *(const short8*)(wsyb + (size_t)(v0 + fv * 16 + lr) * 64 + ks * 32 + lg * 8);
#pragma unroll
        for (int fv = 0; fv < 4; fv++)
#pragma unroll
          for (int fm = 0; fm < 4; fm++)
            acc[fv][fm] = __builtin_amdgcn_mfma_f32_16x16x32_bf16(bf_[fv], af[fm], acc[fv][fm], 0, 0, 0);
      }

#pragma unroll
      for (int fv = 0; fv < 4; fv++) {
        int vb4 = v0 + fv * 16 + lg * 4;
        bool ok = (vb4 + 3) < VV;
        float4 bv = ok ? *(const float4*)(ybias + vb4) : float4{0.f, 0.f, 0.f, 0.f};
#pragma unroll
        for (int fm = 0; fm < 4; fm++) {
          int m = m0 + fm * 16 + lr;
          if (ok) {
            float4 o;
            o.x = acc[fv][fm][0] + bv.x;
            o.y = acc[fv][fm][1] + bv.y;
            o.z = acc[fv][fm][2] + bv.z;
            o.w = acc[fv][fm][3] + bv.w;
            *(float4*)(y + (size_t)m * (size_t)VV + vb4) = o;
          }
        }
      }
    }
  }
}

extern "C" void kernel_launch(void* const* d_in, const int* in_sizes, int n_in,
                              void* d_out, int out_size, void* d_ws, size_t ws_size,
                              hipStream_t stream) {
  const float* x     = (const float*)d_in[0];
  const float* Wxs_w = (const float*)d_in[1];
  const float* Wxs_b = (const float*)d_in[2];
  const float* Wss_w = (const float*)d_in[3];
  const float* Wss_b = (const float*)d_in[4];
  const float* Wsy_w = (const float*)d_in[5];
  const float* Wsy_b = (const float*)d_in[6];
  float* y = (float*)d_out;
  char* ws = (char*)d_ws;

  u16*   xhi   = (u16*)(ws + OFF_XHI);
  u16*   xlo   = (u16*)(ws + OFF_XLO);
  u16*   whi   = (u16*)(ws + OFF_WHI);
  u16*   wlo   = (u16*)(ws + OFF_WLO);
  u16*   wsyb  = (u16*)(ws + OFF_WSY);
  float* xproj = (float*)(ws + OFF_XPROJ);
  u16*   hsb   = (u16*)(ws + OFF_HS);
  int*   prog  = (int*)(ws + OFF_PROG);

  k0_convert<<<(NX + NW + NP) / 256 + 1, 256, 0, stream>>>(
      x, Wxs_w, Wsy_w, xhi, xlo, whi, wlo, wsyb, prog);
  k1_xproj<<<128, 256, 0, stream>>>(xhi, xlo, whi, wlo, Wxs_b, xproj);
  k23_fused<<<256, 256, 0, stream>>>(xproj, Wss_w, Wss_b, hsb, wsyb, Wsy_b, y, prog);
}